// Round 20
// baseline (344.740 us; speedup 1.0000x reference)
//
#include <hip/hip_runtime.h>
#include <math.h>

// Problem constants
#define SEQ 2048
#define DIM 1024
#define NH 16
#define HDIM 64
#define IDIM 2816
#define NL 2

typedef __attribute__((ext_vector_type(8))) short bf16x8;
typedef __attribute__((ext_vector_type(4))) float f32x4;

__device__ __forceinline__ unsigned short f2bf(float f) {
    unsigned int u = __float_as_uint(f);
    u = (u + 0x7fffu + ((u >> 16) & 1u)) >> 16;   // round-to-nearest-even
    return (unsigned short)u;
}
__device__ __forceinline__ float bf2f(unsigned short u) {
    return __uint_as_float((unsigned int)u << 16);
}

__device__ __forceinline__ void gl_lds16(const void* g, void* l) {
    __builtin_amdgcn_global_load_lds(
        (const __attribute__((address_space(1))) unsigned int*)g,
        (__attribute__((address_space(3))) unsigned int*)l, 16, 0, 0);
}

#define WAITVM(n) asm volatile("s_waitcnt vmcnt(" #n ")" ::: "memory")
#define BARRIER_PIN()                       \
    do {                                    \
        __builtin_amdgcn_s_barrier();       \
        __builtin_amdgcn_sched_barrier(0);  \
    } while (0)

// ---------------------------------------------------------------------------
// RMSNorm: one block per row, 256 threads, float4 loads.
// ---------------------------------------------------------------------------
template <bool BF16OUT>
__global__ __launch_bounds__(256) void rmsnorm_kernel(const float* __restrict__ in,
                                                      const float* __restrict__ w,
                                                      void* __restrict__ out) {
    const int row = blockIdx.x;
    const int t = threadIdx.x;
    const float4 v = ((const float4*)(in + (size_t)row * DIM))[t];
    float ss = v.x * v.x + v.y * v.y + v.z * v.z + v.w * v.w;
#pragma unroll
    for (int m = 1; m < 64; m <<= 1) ss += __shfl_xor(ss, m);
    __shared__ float red[4];
    if ((t & 63) == 0) red[t >> 6] = ss;
    __syncthreads();
    const float tot = red[0] + red[1] + red[2] + red[3];
    const float r = 1.0f / sqrtf(tot * (1.0f / DIM) + 1e-5f);
    const float4 wv = ((const float4*)w)[t];
    float o0 = v.x * r * wv.x, o1 = v.y * r * wv.y;
    float o2 = v.z * r * wv.z, o3 = v.w * r * wv.w;
    if (BF16OUT) {
        ushort4 o = {f2bf(o0), f2bf(o1), f2bf(o2), f2bf(o3)};
        ((ushort4*)((unsigned short*)out + (size_t)row * DIM))[t] = o;
    } else {
        float4 o = {o0, o1, o2, o3};
        ((float4*)((float*)out + (size_t)row * DIM))[t] = o;
    }
}

// ---------------------------------------------------------------------------
// Weight conversion fp32 -> bf16 for ONE layer into contiguous wbuf.
// ---------------------------------------------------------------------------
#define WQKV_OFF 0
#define WO_OFF   3145728
#define W1_OFF   4194304
#define W3_OFF   7077888
#define W2_OFF   9961472
#define WTOT     12845056

__global__ __launch_bounds__(256) void convert_weights_kernel(
    const float* __restrict__ wqkv, const float* __restrict__ wo,
    const float* __restrict__ w1, const float* __restrict__ w3,
    const float* __restrict__ w2, unsigned short* __restrict__ out) {
    const size_t i8 = ((size_t)blockIdx.x * 256 + threadIdx.x) * 8;
    const float* src;
    size_t local;
    if (i8 < WO_OFF)      { src = wqkv; local = i8 - WQKV_OFF; }
    else if (i8 < W1_OFF) { src = wo;   local = i8 - WO_OFF; }
    else if (i8 < W3_OFF) { src = w1;   local = i8 - W1_OFF; }
    else if (i8 < W2_OFF) { src = w3;   local = i8 - W3_OFF; }
    else                  { src = w2;   local = i8 - W2_OFF; }
    const float4 v0 = *(const float4*)(src + local);
    const float4 v1 = *(const float4*)(src + local + 4);
    ushort4 o0 = {f2bf(v0.x), f2bf(v0.y), f2bf(v0.z), f2bf(v0.w)};
    ushort4 o1 = {f2bf(v1.x), f2bf(v1.y), f2bf(v1.z), f2bf(v1.w)};
    *(ushort4*)(out + i8) = o0;
    *(ushort4*)(out + i8 + 4) = o1;
}

// ---------------------------------------------------------------------------
// bf16 MFMA GEMM. Tile BM x BN, BK=64, 2-deep double-buffer, counted vmcnt,
// T2 chunk-XOR swizzle, XCD swizzle with COLUMN-major block mapping.
// COMPILE-TIME K (KC); hoisted fragment offsets; unroll-2 K-loop.
// EPI 1: KSPLIT==1: Cf += acc*ls[col]; KSPLIT>1: atomicAdd(Cf, acc*ls[col])
// EPI 3: Cb = bf16(acc)
// ---------------------------------------------------------------------------
template <int EPI, int BM, int BN, int KSPLIT, int KC>
__global__ __launch_bounds__(256) void mfma_gemm(
    const unsigned short* __restrict__ A,
    const unsigned short* __restrict__ B,
    const unsigned short* __restrict__ Bhi, int nsplit,
    float* __restrict__ Cf,
    unsigned short* __restrict__ Cb,
    const float* __restrict__ ls,
    int N) {
    constexpr int K = KC;
    constexpr int MI = BM / 32;
    constexpr int NJ = BN / 32;
    constexpr int L = (BM + BN) / 32;
    constexpr int NT = K / KSPLIT / 64;
    static_assert(L == 6 || L == 8, "WAITVM literals cover L=6,8");
    __shared__ unsigned short As[2][BM * 64];
    __shared__ unsigned short Bs[2][BN * 64];

    const int tid = threadIdx.x;

    const int nwg = gridDim.x * gridDim.y;
    const int orig = blockIdx.y * gridDim.x + blockIdx.x;
    const int swz = (orig & 7) * (nwg >> 3) + (orig >> 3);
    const int bx = swz / gridDim.y;        // column-major: by fast
    const int by = swz % gridDim.y;
    const int m0 = by * BM;
    const int ncol0 = bx * BN;

    const unsigned short* Bp = B;
    int n0 = ncol0;
    if (n0 >= nsplit) { Bp = Bhi; n0 -= nsplit; }

    const int Koff = (KSPLIT > 1) ? blockIdx.z * (K / KSPLIT) : 0;

    const int r0 = tid >> 3;               // 0..31
    const int cswz = (tid & 7) ^ (r0 & 7); // swizzled source chunk
    const unsigned short* Ag = A + (size_t)(m0 + r0) * K + Koff + cswz * 8;
    const unsigned short* Bg = Bp + (size_t)(n0 + r0) * K + Koff + cswz * 8;

    const int lane = tid & 63;
    const int wid = tid >> 6;
    const int wr = (wid >> 1) * (BM / 2);
    const int wc = (wid & 1) * (BN / 2);
    const int fr = lane & 15;
    const int hi = lane >> 4;

    // hoisted fragment LDS offsets (elements), t/buf-invariant
    int offA[MI][2], offB[NJ][2];
#pragma unroll
    for (int m = 0; m < MI; ++m)
#pragma unroll
        for (int kw = 0; kw < 2; ++kw) {
            const int R = wr + m * 16 + fr, c = kw * 4 + hi;
            offA[m][kw] = R * 64 + ((c ^ (R & 7)) << 3);
        }
#pragma unroll
    for (int n = 0; n < NJ; ++n)
#pragma unroll
        for (int kw = 0; kw < 2; ++kw) {
            const int R = wc + n * 16 + fr, c = kw * 4 + hi;
            offB[n][kw] = R * 64 + ((c ^ (R & 7)) << 3);
        }

    f32x4 acc[MI][NJ] = {};

    auto stage = [&](int buf, int kk) {
#pragma unroll
        for (int q = 0; q < BM / 32; ++q)
            gl_lds16(Ag + (size_t)(q * 32) * K + kk, &As[buf][q * 2048 + tid * 8]);
#pragma unroll
        for (int q = 0; q < BN / 32; ++q)
            gl_lds16(Bg + (size_t)(q * 32) * K + kk, &Bs[buf][q * 2048 + tid * 8]);
    };

    auto compute_tile = [&](int buf) {
        bf16x8 a[MI][2], b[NJ][2];
#pragma unroll
        for (int m = 0; m < MI; ++m)
#pragma unroll
            for (int kw = 0; kw < 2; ++kw)
                a[m][kw] = *(const bf16x8*)&As[buf][offA[m][kw]];
#pragma unroll
        for (int n = 0; n < NJ; ++n)
#pragma unroll
            for (int kw = 0; kw < 2; ++kw)
                b[n][kw] = *(const bf16x8*)&Bs[buf][offB[n][kw]];
        __builtin_amdgcn_s_setprio(1);
#pragma unroll
        for (int kw = 0; kw < 2; ++kw)
#pragma unroll
            for (int m = 0; m < MI; ++m)
#pragma unroll
                for (int n = 0; n < NJ; ++n)
                    acc[m][n] = __builtin_amdgcn_mfma_f32_16x16x32_bf16(
                        a[m][kw], b[n][kw], acc[m][n], 0, 0, 0);
        __builtin_amdgcn_s_setprio(0);
    };

    stage(0, 0);
    stage(1, 64);

    int buf = 0;
#pragma unroll 2
    for (int t = 0; t < NT - 1; ++t) {
        if constexpr (L == 6) WAITVM(6); else WAITVM(8);
        BARRIER_PIN();
        compute_tile(buf);
        asm volatile("s_waitcnt lgkmcnt(0)" ::: "memory");
        BARRIER_PIN();
        if (t + 2 < NT) stage(buf, (t + 2) * 64);
        buf ^= 1;
    }
    WAITVM(0);
    BARRIER_PIN();
    compute_tile(buf);

    const int erow = m0 + wr + hi * 4;
    const int ecol = ncol0 + wc + fr;
#pragma unroll
    for (int m = 0; m < MI; ++m) {
#pragma unroll
        for (int n = 0; n < NJ; ++n) {
            const f32x4 v = acc[m][n];
            const int row = erow + m * 16;
            const int col = ecol + n * 16;
            if (EPI == 1) {
                const float lv = ls[col];
#pragma unroll
                for (int j = 0; j < 4; ++j) {
                    float* p = Cf + (size_t)(row + j) * N + col;
                    if (KSPLIT > 1) atomicAdd(p, v[j] * lv);
                    else            *p = *p + v[j] * lv;
                }
            } else {
#pragma unroll
                for (int j = 0; j < 4; ++j)
                    Cb[(size_t)(row + j) * N + col] = f2bf(v[j]);
            }
        }
    }
}

// ---------------------------------------------------------------------------
// FUSED W1/W3 GEMM + silu-mul epilogue. Tile 64x128, BK=64 (was 32 — halves
// the barrier-pair count: NT 32->16, 32 MFMA per pair), dual-B, 1x4 wave
// split, 704 blocks. LDS 16+32+32 = 80 KB -> 2 blocks/CU (matches measured
// effective occupancy, so no loss). Rows are natively 64 elems -> reuses the
// PROVEN main-GEMM chunk-XOR layout (off = R*64 + ((c^(R&7))<<3)).
// Stage per tile: A 2 issues + B1 4 + B3 4 = L=10; steady WAITVM(10).
// out[s][n] = silu(A@w1^T) * (A@w3^T).
// ---------------------------------------------------------------------------
template <int KC>
__global__ __launch_bounds__(256) void mfma_gemm_fused13(
    const unsigned short* __restrict__ A,
    const unsigned short* __restrict__ B1,
    const unsigned short* __restrict__ B3,
    unsigned short* __restrict__ Out,
    int N) {
    constexpr int K = KC;
    constexpr int NT = K / 64;             // 16
    __shared__ unsigned short As[2][64 * 64];
    __shared__ unsigned short Bs[2][128 * 64];
    __shared__ unsigned short B2s[2][128 * 64];

    const int tid = threadIdx.x;

    const int nwg = gridDim.x * gridDim.y;
    const int orig = blockIdx.y * gridDim.x + blockIdx.x;
    const int swz = (orig & 7) * (nwg >> 3) + (orig >> 3);
    const int bx = swz / gridDim.y;        // column-major: by fast
    const int by = swz % gridDim.y;
    const int m0 = by * 64;
    const int n0 = bx * 128;

    // staging (main-GEMM pattern): row q*32 + (tid>>3), chunk (tid&7)^(row&7)
    const int r0 = tid >> 3;               // 0..31
    const int cswz = (tid & 7) ^ (r0 & 7);
    const unsigned short* Ag = A + (size_t)(m0 + r0) * K + cswz * 8;
    const unsigned short* B1g = B1 + (size_t)(n0 + r0) * K + cswz * 8;
    const unsigned short* B3g = B3 + (size_t)(n0 + r0) * K + cswz * 8;

    const int lane = tid & 63;
    const int wid = tid >> 6;
    const int wc = wid * 32;               // 1x4 wave split: all M, 32 cols
    const int fr = lane & 15;
    const int hi = lane >> 4;

    // hoisted fragment LDS offsets (elements)
    int offA[4][2], offB[2][2];
#pragma unroll
    for (int m = 0; m < 4; ++m)
#pragma unroll
        for (int kw = 0; kw < 2; ++kw) {
            const int R = m * 16 + fr, c = kw * 4 + hi;
            offA[m][kw] = R * 64 + ((c ^ (R & 7)) << 3);
        }
#pragma unroll
    for (int n = 0; n < 2; ++n)
#pragma unroll
        for (int kw = 0; kw < 2; ++kw) {
            const int R = wc + n * 16 + fr, c = kw * 4 + hi;
            offB[n][kw] = R * 64 + ((c ^ (R & 7)) << 3);
        }

    f32x4 acc[4][2] = {};
    f32x4 acc2[4][2] = {};

    auto stage = [&](int buf, int kk) {
#pragma unroll
        for (int q = 0; q < 2; ++q)
            gl_lds16(Ag + (size_t)(q * 32) * K + kk, &As[buf][q * 2048 + tid * 8]);
#pragma unroll
        for (int q = 0; q < 4; ++q)
            gl_lds16(B1g + (size_t)(q * 32) * K + kk, &Bs[buf][q * 2048 + tid * 8]);
#pragma unroll
        for (int q = 0; q < 4; ++q)
            gl_lds16(B3g + (size_t)(q * 32) * K + kk, &B2s[buf][q * 2048 + tid * 8]);
    };

    auto compute_tile = [&](int buf) {
        bf16x8 a[4][2], b[2][2], b2[2][2];
#pragma unroll
        for (int m = 0; m < 4; ++m)
#pragma unroll
            for (int kw = 0; kw < 2; ++kw)
                a[m][kw] = *(const bf16x8*)&As[buf][offA[m][kw]];
#pragma unroll
        for (int n = 0; n < 2; ++n)
#pragma unroll
            for (int kw = 0; kw < 2; ++kw) {
                b[n][kw] = *(const bf16x8*)&Bs[buf][offB[n][kw]];
                b2[n][kw] = *(const bf16x8*)&B2s[buf][offB[n][kw]];
            }
        __builtin_amdgcn_s_setprio(1);
#pragma unroll
        for (int kw = 0; kw < 2; ++kw) {
#pragma unroll
            for (int m = 0; m < 4; ++m)
#pragma unroll
                for (int n = 0; n < 2; ++n)
                    acc[m][n] = __builtin_amdgcn_mfma_f32_16x16x32_bf16(
                        a[m][kw], b[n][kw], acc[m][n], 0, 0, 0);
#pragma unroll
            for (int m = 0; m < 4; ++m)
#pragma unroll
                for (int n = 0; n < 2; ++n)
                    acc2[m][n] = __builtin_amdgcn_mfma_f32_16x16x32_bf16(
                        a[m][kw], b2[n][kw], acc2[m][n], 0, 0, 0);
        }
        __builtin_amdgcn_s_setprio(0);
    };

    stage(0, 0);
    stage(1, 64);

    int buf = 0;
#pragma unroll 2
    for (int t = 0; t < NT - 1; ++t) {
        WAITVM(10);                         // tile t resident (t+1's 10 remain)
        BARRIER_PIN();
        compute_tile(buf);
        asm volatile("s_waitcnt lgkmcnt(0)" ::: "memory");
        BARRIER_PIN();
        if (t + 2 < NT) stage(buf, (t + 2) * 64);
        buf ^= 1;
    }
    WAITVM(0);
    BARRIER_PIN();
    compute_tile(buf);

    const int erow = m0 + hi * 4;
    const int ecol = n0 + wc + fr;
#pragma unroll
    for (int m = 0; m < 4; ++m) {
#pragma unroll
        for (int n = 0; n < 2; ++n) {
            const f32x4 g = acc[m][n];
            const f32x4 u = acc2[m][n];
            const int row = erow + m * 16;
            const int col = ecol + n * 16;
#pragma unroll
            for (int j = 0; j < 4; ++j) {
                const float x = g[j];
                Out[(size_t)(row + j) * N + col] =
                    f2bf(x / (1.0f + __expf(-x)) * u[j]);
            }
        }
    }
}

// ---------------------------------------------------------------------------
// RoPE + head-split + V-transpose. Reads bf16 qkv [S][3*DIM]; writes
// Qh,Kh [H][S][HD] (rope'd, bf16) and Vt [H][HD][S] (bf16, LDS-transposed).
// ---------------------------------------------------------------------------
__global__ __launch_bounds__(256) void rope_split_kernel(
    const unsigned short* __restrict__ qkv,
    unsigned short* __restrict__ Qh,
    unsigned short* __restrict__ Kh,
    unsigned short* __restrict__ Vt) {
    const int st = blockIdx.x;
    const int h = blockIdx.y;
    const int tid = threadIdx.x;
    const int srow = tid >> 2;
    const int scol = (tid & 3) * 16;
    const int s = st * 64 + srow;
    __shared__ unsigned short Vl[64][72];

    const unsigned short* base = qkv + (size_t)s * (3 * DIM) + h * HDIM + scol;

    unsigned short qv[16], kv[16], vv[16];
    *(bf16x8*)&qv[0] = *(const bf16x8*)(base);
    *(bf16x8*)&qv[8] = *(const bf16x8*)(base + 8);
    *(bf16x8*)&kv[0] = *(const bf16x8*)(base + DIM);
    *(bf16x8*)&kv[8] = *(const bf16x8*)(base + DIM + 8);
    *(bf16x8*)&vv[0] = *(const bf16x8*)(base + 2 * DIM);
    *(bf16x8*)&vv[8] = *(const bf16x8*)(base + 2 * DIM + 8);

    // -2*ln(10000)/64
    const float FC = -0.28782313662425572f;
    unsigned short qo[16], ko[16];
#pragma unroll
    for (int i = 0; i < 8; ++i) {
        const int p = scol / 2 + i;
        const float freq = __expf(FC * (float)p);
        const float ang = (float)s * freq;
        float sn, cs;
        sincosf(ang, &sn, &cs);
        const float q0 = bf2f(qv[2 * i]), q1 = bf2f(qv[2 * i + 1]);
        const float k0 = bf2f(kv[2 * i]), k1 = bf2f(kv[2 * i + 1]);
        qo[2 * i]     = f2bf(q0 * cs - q1 * sn);
        qo[2 * i + 1] = f2bf(q1 * cs + q0 * sn);
        ko[2 * i]     = f2bf(k0 * cs - k1 * sn);
        ko[2 * i + 1] = f2bf(k1 * cs + k0 * sn);
    }
    unsigned short* qdst = Qh + ((size_t)h * SEQ + s) * HDIM + scol;
    unsigned short* kdst = Kh + ((size_t)h * SEQ + s) * HDIM + scol;
    *(bf16x8*)qdst = *(const bf16x8*)&qo[0];
    *(bf16x8*)(qdst + 8) = *(const bf16x8*)&qo[8];
    *(bf16x8*)kdst = *(const bf16x8*)&ko[0];
    *(bf16x8*)(kdst + 8) = *(const bf16x8*)&ko[8];

#pragma unroll
    for (int i = 0; i < 16; ++i) Vl[scol + i][srow] = vv[i];
    __syncthreads();
    const int d = tid >> 2;
    const int c0 = (tid & 3) * 16;
    unsigned short* vdst = Vt + ((size_t)h * HDIM + d) * SEQ + st * 64 + c0;
    *(bf16x8*)vdst = *(const bf16x8*)&Vl[d][c0];
    *(bf16x8*)(vdst + 8) = *(const bf16x8*)&Vl[d][c0 + 8];
}

// ---------------------------------------------------------------------------
// MFMA flash attention v2b (bf16 in, fp32 acc, causal). Fixed-max softmax,
// KVBLK=64, double-buffered K/V LDS with reg prefetch, Q direct to regs.
// ---------------------------------------------------------------------------
__global__ __launch_bounds__(256) void attn_mfma_kernel(
    const unsigned short* __restrict__ Qh,
    const unsigned short* __restrict__ Kh,
    const unsigned short* __restrict__ Vt,
    unsigned short* __restrict__ y) {
    const int h = blockIdx.x;
    const int qt = blockIdx.y;
    const int qb = (qt < 16) ? qt : 47 - qt;   // pair-balance remap

    __shared__ unsigned short Kl[2][64][72];
    __shared__ unsigned short Vl[2][64][72];
    __shared__ unsigned short Pl[64][72];

    const int tid = threadIdx.x;
    const int lane = tid & 63;
    const int w = tid >> 6;
    const int fr = lane & 15;
    const int fk = (lane >> 4) * 8;
    const int rg = (lane >> 4) * 4;
    const int srow = tid >> 2;
    const int sc8 = (tid & 3) * 8;

    bf16x8 qa[2];
    {
        const unsigned short* qsrc =
            Qh + ((size_t)h * SEQ + qb * 64 + w * 16 + fr) * HDIM;
        qa[0] = *(const bf16x8*)(qsrc + fk);
        qa[1] = *(const bf16x8*)(qsrc + 32 + fk);
    }

    bf16x8 kr0, kr1, vr0, vr1;
    {
        const unsigned short* ks = Kh + ((size_t)h * SEQ + srow) * HDIM + sc8;
        kr0 = *(const bf16x8*)ks;
        kr1 = *(const bf16x8*)(ks + 32);
        const unsigned short* vs = Vt + ((size_t)h * HDIM + srow) * SEQ + sc8;
        vr0 = *(const bf16x8*)vs;
        vr1 = *(const bf16x8*)(vs + 32);
    }

    float l_[4] = {0.0f, 0.0f, 0.0f, 0.0f};
    f32x4 O[4] = {};

    for (int kb = 0; kb <= qb; ++kb) {
        const int cur = kb & 1;
        if (kb > 0) __syncthreads();
        *(bf16x8*)&Kl[cur][srow][sc8] = kr0;
        *(bf16x8*)&Kl[cur][srow][sc8 + 32] = kr1;
        *(bf16x8*)&Vl[cur][srow][sc8] = vr0;
        *(bf16x8*)&Vl[cur][srow][sc8 + 32] = vr1;
        __syncthreads();

        if (kb < qb) {
            const unsigned short* ks = Kh + ((size_t)h * SEQ + (kb + 1) * 64 + srow) * HDIM + sc8;
            kr0 = *(const bf16x8*)ks;
            kr1 = *(const bf16x8*)(ks + 32);
            const unsigned short* vs = Vt + ((size_t)h * HDIM + srow) * SEQ + (kb + 1) * 64 + sc8;
            vr0 = *(const bf16x8*)vs;
            vr1 = *(const bf16x8*)(vs + 32);
        }

        f32x4 sa[4] = {};
        __builtin_amdgcn_s_setprio(1);
#pragma unroll
        for (int ks2 = 0; ks2 < 2; ++ks2)
#pragma unroll
            for (int n = 0; n < 4; ++n) {
                const bf16x8 kf = *(const bf16x8*)&Kl[cur][n * 16 + fr][ks2 * 32 + fk];
                sa[n] = __builtin_amdgcn_mfma_f32_16x16x32_bf16(qa[ks2], kf, sa[n], 0, 0, 0);
            }
        __builtin_amdgcn_s_setprio(0);

        const bool diag = (kb == qb);
#pragma unroll
        for (int n = 0; n < 4; ++n) {
            const int col = n * 16 + fr;
#pragma unroll
            for (int j = 0; j < 4; ++j) {
                const float sv = sa[n][j] * 0.125f;
                float e = __expf(fminf(sv, 30.0f));
                if (diag && col > rg + j) e = 0.0f;
                l_[j] += e;
                Pl[w * 16 + rg + j][col] = f2bf(e);
            }
        }

        __builtin_amdgcn_s_setprio(1);
#pragma unroll
        for (int ks2 = 0; ks2 < 2; ++ks2) {
            const bf16x8 pa = *(const bf16x8*)&Pl[w * 16 + fr][ks2 * 32 + fk];
#pragma unroll
            for (int nd = 0; nd < 4; ++nd) {
                const bf16x8 vf = *(const bf16x8*)&Vl[cur][nd * 16 + fr][ks2 * 32 + fk];
                O[nd] = __builtin_amdgcn_mfma_f32_16x16x32_bf16(pa, vf, O[nd], 0, 0, 0);
            }
        }
        __builtin_amdgcn_s_setprio(0);
    }

#pragma unroll
    for (int j = 0; j < 4; ++j) {
#pragma unroll
        for (int msk = 1; msk < 16; msk <<= 1) l_[j] += __shfl_xor(l_[j], msk);
    }

#pragma unroll
    for (int j = 0; j < 4; ++j) {
        const float inv = 1.0f / l_[j];
        unsigned short* dst = y + (size_t)(qb * 64 + w * 16 + rg + j) * DIM + h * HDIM + fr;
#pragma unroll
        for (int nd = 0; nd < 4; ++nd)
            dst[nd * 16] = f2bf(O[nd][j] * inv);
    }
}

// ---------------------------------------------------------------------------
// Host launcher
// ---------------------------------------------------------------------------
extern "C" void kernel_launch(void* const* d_in, const int* in_sizes, int n_in,
                              void* d_out, int out_size, void* d_ws, size_t ws_size,
                              hipStream_t stream) {
    const float* x            = (const float*)d_in[0];
    const float* wqkv         = (const float*)d_in[1];
    const float* wo           = (const float*)d_in[2];
    const float* w1           = (const float*)d_in[3];
    const float* w2           = (const float*)d_in[4];
    const float* w3           = (const float*)d_in[5];
    const float* attn_norm_w  = (const float*)d_in[6];
    const float* ffn_norm_w   = (const float*)d_in[7];
    const float* attn_ls      = (const float*)d_in[8];
    const float* ffn_ls       = (const float*)d_in[9];
    const float* final_norm_w = (const float*)d_in[10];
    float* out = (float*)d_out;

    // Workspace layout (bytes):
    //   h    f32  [0,        8388608)
    //   xnb  bf16 [8388608, 12582912)
    //   yb   bf16 [12582912,16777216)
    //   scratch   [16777216,41943040): qkvb | Qh | Kh | Vt
    //   ffb  bf16 [41943040,46137344)
    //   wbuf bf16 [46137344,71827456)
    char* ws = (char*)d_ws;
    float*          h     = (float*)ws;
    unsigned short* xnb   = (unsigned short*)(ws + 8388608);
    unsigned short* yb    = (unsigned short*)(ws + 12582912);
    unsigned short* qkvb  = (unsigned short*)(ws + 16777216);
    unsigned short* Qhb   = (unsigned short*)(ws + 29360128);
    unsigned short* Khb   = (unsigned short*)(ws + 33554432);
    unsigned short* Vtb   = (unsigned short*)(ws + 37748736);
    unsigned short* ffb   = (unsigned short*)(ws + 41943040);
    unsigned short* wbuf  = (unsigned short*)(ws + 46137344);

    unsigned short* wqkv_b = wbuf + WQKV_OFF;
    unsigned short* wo_b   = wbuf + WO_OFF;
    unsigned short* w1_b   = wbuf + W1_OFF;
    unsigned short* w3_b   = wbuf + W3_OFF;
    unsigned short* w2_b   = wbuf + W2_OFF;

    const int BIG = 1 << 30;

    hipMemcpyAsync(h, x, (size_t)SEQ * DIM * sizeof(float),
                   hipMemcpyDeviceToDevice, stream);

    for (int l = 0; l < NL; ++l) {
        convert_weights_kernel<<<WTOT / 2048, 256, 0, stream>>>(
            wqkv + (size_t)l * 3 * DIM * DIM, wo + (size_t)l * DIM * DIM,
            w1 + (size_t)l * IDIM * DIM, w3 + (size_t)l * IDIM * DIM,
            w2 + (size_t)l * DIM * IDIM, wbuf);

        // ---- attention block ----
        rmsnorm_kernel<true><<<SEQ, 256, 0, stream>>>(h, attn_norm_w + l * DIM, xnb);
        // QKV: 64x128, 768 blocks (3/CU)
        mfma_gemm<3, 64, 128, 1, DIM><<<dim3(3 * DIM / 128, SEQ / 64), 256, 0, stream>>>(
            xnb, wqkv_b, nullptr, BIG, nullptr, qkvb, nullptr, 3 * DIM);
        rope_split_kernel<<<dim3(SEQ / 64, NH), 256, 0, stream>>>(qkvb, Qhb, Khb, Vtb);
        attn_mfma_kernel<<<dim3(NH, SEQ / 64), 256, 0, stream>>>(Qhb, Khb, Vtb, yb);
        // WO: 64x128, split-K=2, atomic residual+ls (512 blocks)
        mfma_gemm<1, 64, 128, 2, DIM><<<dim3(DIM / 128, SEQ / 64, 2), 256, 0, stream>>>(
            yb, wo_b, nullptr, BIG, h, nullptr, attn_ls + l * DIM, DIM);

        // ---- FFN block ----
        rmsnorm_kernel<true><<<SEQ, 256, 0, stream>>>(h, ffn_norm_w + l * DIM, xnb);
        // FUSED W1/W3 + silu: 64x128/BK64 dual-B, 1x4 waves, 704 blocks
        mfma_gemm_fused13<DIM><<<dim3(IDIM / 128, SEQ / 64), 256, 0, stream>>>(
            xnb, w1_b, w3_b, ffb, IDIM);
        // W2: 64x128, split-K=2, atomic residual+ls (512 blocks)
        mfma_gemm<1, 64, 128, 2, IDIM><<<dim3(DIM / 128, SEQ / 64, 2), 256, 0, stream>>>(
            ffb, w2_b, nullptr, BIG, h, nullptr, ffn_ls + l * DIM, DIM);
    }

    rmsnorm_kernel<false><<<SEQ, 256, 0, stream>>>(h, final_norm_w, out);
}

// Round 21
// 336.534 us; speedup vs baseline: 1.0244x; 1.0244x over previous
//
#include <hip/hip_runtime.h>
#include <math.h>

// Problem constants
#define SEQ 2048
#define DIM 1024
#define NH 16
#define HDIM 64
#define IDIM 2816
#define NL 2

typedef __attribute__((ext_vector_type(8))) short bf16x8;
typedef __attribute__((ext_vector_type(4))) float f32x4;

__device__ __forceinline__ unsigned short f2bf(float f) {
    unsigned int u = __float_as_uint(f);
    u = (u + 0x7fffu + ((u >> 16) & 1u)) >> 16;   // round-to-nearest-even
    return (unsigned short)u;
}
__device__ __forceinline__ float bf2f(unsigned short u) {
    return __uint_as_float((unsigned int)u << 16);
}

__device__ __forceinline__ void gl_lds16(const void* g, void* l) {
    __builtin_amdgcn_global_load_lds(
        (const __attribute__((address_space(1))) unsigned int*)g,
        (__attribute__((address_space(3))) unsigned int*)l, 16, 0, 0);
}

#define WAITVM(n) asm volatile("s_waitcnt vmcnt(" #n ")" ::: "memory")
#define BARRIER_PIN()                       \
    do {                                    \
        __builtin_amdgcn_s_barrier();       \
        __builtin_amdgcn_sched_barrier(0);  \
    } while (0)

// ---------------------------------------------------------------------------
// RMSNorm: one block per row, 256 threads, float4 loads.
// ---------------------------------------------------------------------------
template <bool BF16OUT>
__global__ __launch_bounds__(256) void rmsnorm_kernel(const float* __restrict__ in,
                                                      const float* __restrict__ w,
                                                      void* __restrict__ out) {
    const int row = blockIdx.x;
    const int t = threadIdx.x;
    const float4 v = ((const float4*)(in + (size_t)row * DIM))[t];
    float ss = v.x * v.x + v.y * v.y + v.z * v.z + v.w * v.w;
#pragma unroll
    for (int m = 1; m < 64; m <<= 1) ss += __shfl_xor(ss, m);
    __shared__ float red[4];
    if ((t & 63) == 0) red[t >> 6] = ss;
    __syncthreads();
    const float tot = red[0] + red[1] + red[2] + red[3];
    const float r = 1.0f / sqrtf(tot * (1.0f / DIM) + 1e-5f);
    const float4 wv = ((const float4*)w)[t];
    float o0 = v.x * r * wv.x, o1 = v.y * r * wv.y;
    float o2 = v.z * r * wv.z, o3 = v.w * r * wv.w;
    if (BF16OUT) {
        ushort4 o = {f2bf(o0), f2bf(o1), f2bf(o2), f2bf(o3)};
        ((ushort4*)((unsigned short*)out + (size_t)row * DIM))[t] = o;
    } else {
        float4 o = {o0, o1, o2, o3};
        ((float4*)((float*)out + (size_t)row * DIM))[t] = o;
    }
}

// ---------------------------------------------------------------------------
// Weight conversion fp32 -> bf16 for ONE layer into contiguous wbuf.
// ---------------------------------------------------------------------------
#define WQKV_OFF 0
#define WO_OFF   3145728
#define W1_OFF   4194304
#define W3_OFF   7077888
#define W2_OFF   9961472
#define WTOT     12845056

__global__ __launch_bounds__(256) void convert_weights_kernel(
    const float* __restrict__ wqkv, const float* __restrict__ wo,
    const float* __restrict__ w1, const float* __restrict__ w3,
    const float* __restrict__ w2, unsigned short* __restrict__ out) {
    const size_t i8 = ((size_t)blockIdx.x * 256 + threadIdx.x) * 8;
    const float* src;
    size_t local;
    if (i8 < WO_OFF)      { src = wqkv; local = i8 - WQKV_OFF; }
    else if (i8 < W1_OFF) { src = wo;   local = i8 - WO_OFF; }
    else if (i8 < W3_OFF) { src = w1;   local = i8 - W1_OFF; }
    else if (i8 < W2_OFF) { src = w3;   local = i8 - W3_OFF; }
    else                  { src = w2;   local = i8 - W2_OFF; }
    const float4 v0 = *(const float4*)(src + local);
    const float4 v1 = *(const float4*)(src + local + 4);
    ushort4 o0 = {f2bf(v0.x), f2bf(v0.y), f2bf(v0.z), f2bf(v0.w)};
    ushort4 o1 = {f2bf(v1.x), f2bf(v1.y), f2bf(v1.z), f2bf(v1.w)};
    *(ushort4*)(out + i8) = o0;
    *(ushort4*)(out + i8 + 4) = o1;
}

// ---------------------------------------------------------------------------
// bf16 MFMA GEMM. Tile BM x BN, BK=64, 2-deep double-buffer, counted vmcnt,
// T2 chunk-XOR swizzle, XCD swizzle with COLUMN-major block mapping.
// COMPILE-TIME K (KC); hoisted fragment offsets; unroll-2 K-loop.
// EPI 1: KSPLIT==1: Cf += acc*ls[col]; KSPLIT>1: atomicAdd(Cf, acc*ls[col])
// EPI 3: Cb = bf16(acc)
// ---------------------------------------------------------------------------
template <int EPI, int BM, int BN, int KSPLIT, int KC>
__global__ __launch_bounds__(256) void mfma_gemm(
    const unsigned short* __restrict__ A,
    const unsigned short* __restrict__ B,
    const unsigned short* __restrict__ Bhi, int nsplit,
    float* __restrict__ Cf,
    unsigned short* __restrict__ Cb,
    const float* __restrict__ ls,
    int N) {
    constexpr int K = KC;
    constexpr int MI = BM / 32;
    constexpr int NJ = BN / 32;
    constexpr int L = (BM + BN) / 32;
    constexpr int NT = K / KSPLIT / 64;
    static_assert(L == 6 || L == 8, "WAITVM literals cover L=6,8");
    __shared__ unsigned short As[2][BM * 64];
    __shared__ unsigned short Bs[2][BN * 64];

    const int tid = threadIdx.x;

    const int nwg = gridDim.x * gridDim.y;
    const int orig = blockIdx.y * gridDim.x + blockIdx.x;
    const int swz = (orig & 7) * (nwg >> 3) + (orig >> 3);
    const int bx = swz / gridDim.y;        // column-major: by fast
    const int by = swz % gridDim.y;
    const int m0 = by * BM;
    const int ncol0 = bx * BN;

    const unsigned short* Bp = B;
    int n0 = ncol0;
    if (n0 >= nsplit) { Bp = Bhi; n0 -= nsplit; }

    const int Koff = (KSPLIT > 1) ? blockIdx.z * (K / KSPLIT) : 0;

    const int r0 = tid >> 3;               // 0..31
    const int cswz = (tid & 7) ^ (r0 & 7); // swizzled source chunk
    const unsigned short* Ag = A + (size_t)(m0 + r0) * K + Koff + cswz * 8;
    const unsigned short* Bg = Bp + (size_t)(n0 + r0) * K + Koff + cswz * 8;

    const int lane = tid & 63;
    const int wid = tid >> 6;
    const int wr = (wid >> 1) * (BM / 2);
    const int wc = (wid & 1) * (BN / 2);
    const int fr = lane & 15;
    const int hi = lane >> 4;

    // hoisted fragment LDS offsets (elements), t/buf-invariant
    int offA[MI][2], offB[NJ][2];
#pragma unroll
    for (int m = 0; m < MI; ++m)
#pragma unroll
        for (int kw = 0; kw < 2; ++kw) {
            const int R = wr + m * 16 + fr, c = kw * 4 + hi;
            offA[m][kw] = R * 64 + ((c ^ (R & 7)) << 3);
        }
#pragma unroll
    for (int n = 0; n < NJ; ++n)
#pragma unroll
        for (int kw = 0; kw < 2; ++kw) {
            const int R = wc + n * 16 + fr, c = kw * 4 + hi;
            offB[n][kw] = R * 64 + ((c ^ (R & 7)) << 3);
        }

    f32x4 acc[MI][NJ] = {};

    auto stage = [&](int buf, int kk) {
#pragma unroll
        for (int q = 0; q < BM / 32; ++q)
            gl_lds16(Ag + (size_t)(q * 32) * K + kk, &As[buf][q * 2048 + tid * 8]);
#pragma unroll
        for (int q = 0; q < BN / 32; ++q)
            gl_lds16(Bg + (size_t)(q * 32) * K + kk, &Bs[buf][q * 2048 + tid * 8]);
    };

    auto compute_tile = [&](int buf) {
        bf16x8 a[MI][2], b[NJ][2];
#pragma unroll
        for (int m = 0; m < MI; ++m)
#pragma unroll
            for (int kw = 0; kw < 2; ++kw)
                a[m][kw] = *(const bf16x8*)&As[buf][offA[m][kw]];
#pragma unroll
        for (int n = 0; n < NJ; ++n)
#pragma unroll
            for (int kw = 0; kw < 2; ++kw)
                b[n][kw] = *(const bf16x8*)&Bs[buf][offB[n][kw]];
        __builtin_amdgcn_s_setprio(1);
#pragma unroll
        for (int kw = 0; kw < 2; ++kw)
#pragma unroll
            for (int m = 0; m < MI; ++m)
#pragma unroll
                for (int n = 0; n < NJ; ++n)
                    acc[m][n] = __builtin_amdgcn_mfma_f32_16x16x32_bf16(
                        a[m][kw], b[n][kw], acc[m][n], 0, 0, 0);
        __builtin_amdgcn_s_setprio(0);
    };

    stage(0, 0);
    stage(1, 64);

    int buf = 0;
#pragma unroll 2
    for (int t = 0; t < NT - 1; ++t) {
        if constexpr (L == 6) WAITVM(6); else WAITVM(8);
        BARRIER_PIN();
        compute_tile(buf);
        asm volatile("s_waitcnt lgkmcnt(0)" ::: "memory");
        BARRIER_PIN();
        if (t + 2 < NT) stage(buf, (t + 2) * 64);
        buf ^= 1;
    }
    WAITVM(0);
    BARRIER_PIN();
    compute_tile(buf);

    const int erow = m0 + wr + hi * 4;
    const int ecol = ncol0 + wc + fr;
#pragma unroll
    for (int m = 0; m < MI; ++m) {
#pragma unroll
        for (int n = 0; n < NJ; ++n) {
            const f32x4 v = acc[m][n];
            const int row = erow + m * 16;
            const int col = ecol + n * 16;
            if (EPI == 1) {
                const float lv = ls[col];
#pragma unroll
                for (int j = 0; j < 4; ++j) {
                    float* p = Cf + (size_t)(row + j) * N + col;
                    if (KSPLIT > 1) atomicAdd(p, v[j] * lv);
                    else            *p = *p + v[j] * lv;
                }
            } else {
#pragma unroll
                for (int j = 0; j < 4; ++j)
                    Cb[(size_t)(row + j) * N + col] = f2bf(v[j]);
            }
        }
    }
}

// ---------------------------------------------------------------------------
// FUSED W1/W3 GEMM + silu-mul epilogue. Tile 64x128, BK=32, dual-B,
// 1x4 wave split, 704 blocks, LDS 40 KB. COMPILE-TIME K; hoisted offsets.
// (Round-19 proven config; BK=64 variant regressed via occupancy+L2 loss.)
// out[s][n] = silu(A@w1^T) * (A@w3^T).
// LDS virtual-row layout: elem(R, c in 0..3): vr=R>>1,
//   slot=((R&1)*4+c)^(vr&7), offset = vr*64 + slot*8.
// Stage: issue q covers vr q*32+(tid>>3); uc=(tid&7)^((tid>>3)&7);
// global row = q*64 + 2*(tid>>3)+(uc>>2), k-chunk = uc&3;
// LDS dest = q*2048 + tid*8. A: 1 issue; B1,B3: 2 each -> L=5, WAITVM(5).
// ---------------------------------------------------------------------------
template <int KC>
__global__ __launch_bounds__(256) void mfma_gemm_fused13(
    const unsigned short* __restrict__ A,
    const unsigned short* __restrict__ B1,
    const unsigned short* __restrict__ B3,
    unsigned short* __restrict__ Out,
    int N) {
    constexpr int K = KC;
    constexpr int NT = K / 32;
    __shared__ unsigned short As[2][64 * 32];
    __shared__ unsigned short Bs[2][128 * 32];
    __shared__ unsigned short B2s[2][128 * 32];

    const int tid = threadIdx.x;

    const int nwg = gridDim.x * gridDim.y;
    const int orig = blockIdx.y * gridDim.x + blockIdx.x;
    const int swz = (orig & 7) * (nwg >> 3) + (orig >> 3);
    const int bx = swz / gridDim.y;        // column-major: by fast
    const int by = swz % gridDim.y;
    const int m0 = by * 64;
    const int n0 = bx * 128;

    const int uc = (tid & 7) ^ ((tid >> 3) & 7);
    const int srow = 2 * (tid >> 3) + (uc >> 2);
    const int skof = (uc & 3) * 8;
    const unsigned short* Ag = A + (size_t)(m0 + srow) * K + skof;
    const unsigned short* B1g = B1 + (size_t)(n0 + srow) * K + skof;
    const unsigned short* B3g = B3 + (size_t)(n0 + srow) * K + skof;

    const int lane = tid & 63;
    const int wid = tid >> 6;
    const int wc = wid * 32;               // 1x4 wave split
    const int fr = lane & 15;
    const int hi = lane >> 4;

    // hoisted fragment LDS offsets (elements)
    int offA[4], offB[2];
#pragma unroll
    for (int m = 0; m < 4; ++m) {
        const int R = m * 16 + fr;
        const int vr = R >> 1;
        offA[m] = vr * 64 + ((((R & 1) * 4 + hi) ^ (vr & 7)) << 3);
    }
#pragma unroll
    for (int n = 0; n < 2; ++n) {
        const int R = wc + n * 16 + fr;
        const int vr = R >> 1;
        offB[n] = vr * 64 + ((((R & 1) * 4 + hi) ^ (vr & 7)) << 3);
    }

    f32x4 acc[4][2] = {};
    f32x4 acc2[4][2] = {};

    auto stage = [&](int buf, int kk) {
        gl_lds16(Ag + kk, &As[buf][tid * 8]);
#pragma unroll
        for (int q = 0; q < 2; ++q)
            gl_lds16(B1g + (size_t)(q * 64) * K + kk, &Bs[buf][q * 2048 + tid * 8]);
#pragma unroll
        for (int q = 0; q < 2; ++q)
            gl_lds16(B3g + (size_t)(q * 64) * K + kk, &B2s[buf][q * 2048 + tid * 8]);
    };

    auto compute_tile = [&](int buf) {
        bf16x8 a[4], b[2], b2[2];
#pragma unroll
        for (int m = 0; m < 4; ++m)
            a[m] = *(const bf16x8*)&As[buf][offA[m]];
#pragma unroll
        for (int n = 0; n < 2; ++n)
            b[n] = *(const bf16x8*)&Bs[buf][offB[n]];
#pragma unroll
        for (int n = 0; n < 2; ++n)
            b2[n] = *(const bf16x8*)&B2s[buf][offB[n]];
        __builtin_amdgcn_s_setprio(1);
#pragma unroll
        for (int m = 0; m < 4; ++m)
#pragma unroll
            for (int n = 0; n < 2; ++n)
                acc[m][n] = __builtin_amdgcn_mfma_f32_16x16x32_bf16(
                    a[m], b[n], acc[m][n], 0, 0, 0);
#pragma unroll
        for (int m = 0; m < 4; ++m)
#pragma unroll
            for (int n = 0; n < 2; ++n)
                acc2[m][n] = __builtin_amdgcn_mfma_f32_16x16x32_bf16(
                    a[m], b2[n], acc2[m][n], 0, 0, 0);
        __builtin_amdgcn_s_setprio(0);
    };

    stage(0, 0);
    stage(1, 32);

    int buf = 0;
#pragma unroll 2
    for (int t = 0; t < NT - 1; ++t) {
        WAITVM(5);                          // tile t resident (t+1's 5 remain)
        BARRIER_PIN();
        compute_tile(buf);
        asm volatile("s_waitcnt lgkmcnt(0)" ::: "memory");
        BARRIER_PIN();
        if (t + 2 < NT) stage(buf, (t + 2) * 32);
        buf ^= 1;
    }
    WAITVM(0);
    BARRIER_PIN();
    compute_tile(buf);

    const int erow = m0 + hi * 4;
    const int ecol = n0 + wc + fr;
#pragma unroll
    for (int m = 0; m < 4; ++m) {
#pragma unroll
        for (int n = 0; n < 2; ++n) {
            const f32x4 g = acc[m][n];
            const f32x4 u = acc2[m][n];
            const int row = erow + m * 16;
            const int col = ecol + n * 16;
#pragma unroll
            for (int j = 0; j < 4; ++j) {
                const float x = g[j];
                Out[(size_t)(row + j) * N + col] =
                    f2bf(x / (1.0f + __expf(-x)) * u[j]);
            }
        }
    }
}

// ---------------------------------------------------------------------------
// RoPE + head-split + V-transpose. Reads bf16 qkv [S][3*DIM]; writes
// Qh,Kh [H][S][HD] (rope'd, bf16) and Vt [H][HD][S] (bf16, LDS-transposed).
// ---------------------------------------------------------------------------
__global__ __launch_bounds__(256) void rope_split_kernel(
    const unsigned short* __restrict__ qkv,
    unsigned short* __restrict__ Qh,
    unsigned short* __restrict__ Kh,
    unsigned short* __restrict__ Vt) {
    const int st = blockIdx.x;
    const int h = blockIdx.y;
    const int tid = threadIdx.x;
    const int srow = tid >> 2;
    const int scol = (tid & 3) * 16;
    const int s = st * 64 + srow;
    __shared__ unsigned short Vl[64][72];

    const unsigned short* base = qkv + (size_t)s * (3 * DIM) + h * HDIM + scol;

    unsigned short qv[16], kv[16], vv[16];
    *(bf16x8*)&qv[0] = *(const bf16x8*)(base);
    *(bf16x8*)&qv[8] = *(const bf16x8*)(base + 8);
    *(bf16x8*)&kv[0] = *(const bf16x8*)(base + DIM);
    *(bf16x8*)&kv[8] = *(const bf16x8*)(base + DIM + 8);
    *(bf16x8*)&vv[0] = *(const bf16x8*)(base + 2 * DIM);
    *(bf16x8*)&vv[8] = *(const bf16x8*)(base + 2 * DIM + 8);

    // -2*ln(10000)/64
    const float FC = -0.28782313662425572f;
    unsigned short qo[16], ko[16];
#pragma unroll
    for (int i = 0; i < 8; ++i) {
        const int p = scol / 2 + i;
        const float freq = __expf(FC * (float)p);
        const float ang = (float)s * freq;
        float sn, cs;
        sincosf(ang, &sn, &cs);
        const float q0 = bf2f(qv[2 * i]), q1 = bf2f(qv[2 * i + 1]);
        const float k0 = bf2f(kv[2 * i]), k1 = bf2f(kv[2 * i + 1]);
        qo[2 * i]     = f2bf(q0 * cs - q1 * sn);
        qo[2 * i + 1] = f2bf(q1 * cs + q0 * sn);
        ko[2 * i]     = f2bf(k0 * cs - k1 * sn);
        ko[2 * i + 1] = f2bf(k1 * cs + k0 * sn);
    }
    unsigned short* qdst = Qh + ((size_t)h * SEQ + s) * HDIM + scol;
    unsigned short* kdst = Kh + ((size_t)h * SEQ + s) * HDIM + scol;
    *(bf16x8*)qdst = *(const bf16x8*)&qo[0];
    *(bf16x8*)(qdst + 8) = *(const bf16x8*)&qo[8];
    *(bf16x8*)kdst = *(const bf16x8*)&ko[0];
    *(bf16x8*)(kdst + 8) = *(const bf16x8*)&ko[8];

#pragma unroll
    for (int i = 0; i < 16; ++i) Vl[scol + i][srow] = vv[i];
    __syncthreads();
    const int d = tid >> 2;
    const int c0 = (tid & 3) * 16;
    unsigned short* vdst = Vt + ((size_t)h * HDIM + d) * SEQ + st * 64 + c0;
    *(bf16x8*)vdst = *(const bf16x8*)&Vl[d][c0];
    *(bf16x8*)(vdst + 8) = *(const bf16x8*)&Vl[d][c0 + 8];
}

// ---------------------------------------------------------------------------
// MFMA flash attention v2b (bf16 in, fp32 acc, causal). Fixed-max softmax,
// KVBLK=64, double-buffered K/V LDS with reg prefetch, Q direct to regs.
// ---------------------------------------------------------------------------
__global__ __launch_bounds__(256) void attn_mfma_kernel(
    const unsigned short* __restrict__ Qh,
    const unsigned short* __restrict__ Kh,
    const unsigned short* __restrict__ Vt,
    unsigned short* __restrict__ y) {
    const int h = blockIdx.x;
    const int qt = blockIdx.y;
    const int qb = (qt < 16) ? qt : 47 - qt;   // pair-balance remap

    __shared__ unsigned short Kl[2][64][72];
    __shared__ unsigned short Vl[2][64][72];
    __shared__ unsigned short Pl[64][72];

    const int tid = threadIdx.x;
    const int lane = tid & 63;
    const int w = tid >> 6;
    const int fr = lane & 15;
    const int fk = (lane >> 4) * 8;
    const int rg = (lane >> 4) * 4;
    const int srow = tid >> 2;
    const int sc8 = (tid & 3) * 8;

    bf16x8 qa[2];
    {
        const unsigned short* qsrc =
            Qh + ((size_t)h * SEQ + qb * 64 + w * 16 + fr) * HDIM;
        qa[0] = *(const bf16x8*)(qsrc + fk);
        qa[1] = *(const bf16x8*)(qsrc + 32 + fk);
    }

    bf16x8 kr0, kr1, vr0, vr1;
    {
        const unsigned short* ks = Kh + ((size_t)h * SEQ + srow) * HDIM + sc8;
        kr0 = *(const bf16x8*)ks;
        kr1 = *(const bf16x8*)(ks + 32);
        const unsigned short* vs = Vt + ((size_t)h * HDIM + srow) * SEQ + sc8;
        vr0 = *(const bf16x8*)vs;
        vr1 = *(const bf16x8*)(vs + 32);
    }

    float l_[4] = {0.0f, 0.0f, 0.0f, 0.0f};
    f32x4 O[4] = {};

    for (int kb = 0; kb <= qb; ++kb) {
        const int cur = kb & 1;
        if (kb > 0) __syncthreads();
        *(bf16x8*)&Kl[cur][srow][sc8] = kr0;
        *(bf16x8*)&Kl[cur][srow][sc8 + 32] = kr1;
        *(bf16x8*)&Vl[cur][srow][sc8] = vr0;
        *(bf16x8*)&Vl[cur][srow][sc8 + 32] = vr1;
        __syncthreads();

        if (kb < qb) {
            const unsigned short* ks = Kh + ((size_t)h * SEQ + (kb + 1) * 64 + srow) * HDIM + sc8;
            kr0 = *(const bf16x8*)ks;
            kr1 = *(const bf16x8*)(ks + 32);
            const unsigned short* vs = Vt + ((size_t)h * HDIM + srow) * SEQ + (kb + 1) * 64 + sc8;
            vr0 = *(const bf16x8*)vs;
            vr1 = *(const bf16x8*)(vs + 32);
        }

        f32x4 sa[4] = {};
        __builtin_amdgcn_s_setprio(1);
#pragma unroll
        for (int ks2 = 0; ks2 < 2; ++ks2)
#pragma unroll
            for (int n = 0; n < 4; ++n) {
                const bf16x8 kf = *(const bf16x8*)&Kl[cur][n * 16 + fr][ks2 * 32 + fk];
                sa[n] = __builtin_amdgcn_mfma_f32_16x16x32_bf16(qa[ks2], kf, sa[n], 0, 0, 0);
            }
        __builtin_amdgcn_s_setprio(0);

        const bool diag = (kb == qb);
#pragma unroll
        for (int n = 0; n < 4; ++n) {
            const int col = n * 16 + fr;
#pragma unroll
            for (int j = 0; j < 4; ++j) {
                const float sv = sa[n][j] * 0.125f;
                float e = __expf(fminf(sv, 30.0f));
                if (diag && col > rg + j) e = 0.0f;
                l_[j] += e;
                Pl[w * 16 + rg + j][col] = f2bf(e);
            }
        }

        __builtin_amdgcn_s_setprio(1);
#pragma unroll
        for (int ks2 = 0; ks2 < 2; ++ks2) {
            const bf16x8 pa = *(const bf16x8*)&Pl[w * 16 + fr][ks2 * 32 + fk];
#pragma unroll
            for (int nd = 0; nd < 4; ++nd) {
                const bf16x8 vf = *(const bf16x8*)&Vl[cur][nd * 16 + fr][ks2 * 32 + fk];
                O[nd] = __builtin_amdgcn_mfma_f32_16x16x32_bf16(pa, vf, O[nd], 0, 0, 0);
            }
        }
        __builtin_amdgcn_s_setprio(0);
    }

#pragma unroll
    for (int j = 0; j < 4; ++j) {
#pragma unroll
        for (int msk = 1; msk < 16; msk <<= 1) l_[j] += __shfl_xor(l_[j], msk);
    }

#pragma unroll
    for (int j = 0; j < 4; ++j) {
        const float inv = 1.0f / l_[j];
        unsigned short* dst = y + (size_t)(qb * 64 + w * 16 + rg + j) * DIM + h * HDIM + fr;
#pragma unroll
        for (int nd = 0; nd < 4; ++nd)
            dst[nd * 16] = f2bf(O[nd][j] * inv);
    }
}

// ---------------------------------------------------------------------------
// Host launcher
// ---------------------------------------------------------------------------
extern "C" void kernel_launch(void* const* d_in, const int* in_sizes, int n_in,
                              void* d_out, int out_size, void* d_ws, size_t ws_size,
                              hipStream_t stream) {
    const float* x            = (const float*)d_in[0];
    const float* wqkv         = (const float*)d_in[1];
    const float* wo           = (const float*)d_in[2];
    const float* w1           = (const float*)d_in[3];
    const float* w2           = (const float*)d_in[4];
    const float* w3           = (const float*)d_in[5];
    const float* attn_norm_w  = (const float*)d_in[6];
    const float* ffn_norm_w   = (const float*)d_in[7];
    const float* attn_ls      = (const float*)d_in[8];
    const float* ffn_ls       = (const float*)d_in[9];
    const float* final_norm_w = (const float*)d_in[10];
    float* out = (float*)d_out;

    // Workspace layout (bytes):
    //   h    f32  [0,        8388608)
    //   xnb  bf16 [8388608, 12582912)
    //   yb   bf16 [12582912,16777216)
    //   scratch   [16777216,41943040): qkvb | Qh | Kh | Vt
    //   ffb  bf16 [41943040,46137344)
    //   wbuf bf16 [46137344,71827456)
    char* ws = (char*)d_ws;
    float*          h     = (float*)ws;
    unsigned short* xnb   = (unsigned short*)(ws + 8388608);
    unsigned short* yb    = (unsigned short*)(ws + 12582912);
    unsigned short* qkvb  = (unsigned short*)(ws + 16777216);
    unsigned short* Qhb   = (unsigned short*)(ws + 29360128);
    unsigned short* Khb   = (unsigned short*)(ws + 33554432);
    unsigned short* Vtb   = (unsigned short*)(ws + 37748736);
    unsigned short* ffb   = (unsigned short*)(ws + 41943040);
    unsigned short* wbuf  = (unsigned short*)(ws + 46137344);

    unsigned short* wqkv_b = wbuf + WQKV_OFF;
    unsigned short* wo_b   = wbuf + WO_OFF;
    unsigned short* w1_b   = wbuf + W1_OFF;
    unsigned short* w3_b   = wbuf + W3_OFF;
    unsigned short* w2_b   = wbuf + W2_OFF;

    const int BIG = 1 << 30;

    hipMemcpyAsync(h, x, (size_t)SEQ * DIM * sizeof(float),
                   hipMemcpyDeviceToDevice, stream);

    for (int l = 0; l < NL; ++l) {
        convert_weights_kernel<<<WTOT / 2048, 256, 0, stream>>>(
            wqkv + (size_t)l * 3 * DIM * DIM, wo + (size_t)l * DIM * DIM,
            w1 + (size_t)l * IDIM * DIM, w3 + (size_t)l * IDIM * DIM,
            w2 + (size_t)l * DIM * IDIM, wbuf);

        // ---- attention block ----
        rmsnorm_kernel<true><<<SEQ, 256, 0, stream>>>(h, attn_norm_w + l * DIM, xnb);
        // QKV: 64x128, 768 blocks (3/CU)
        mfma_gemm<3, 64, 128, 1, DIM><<<dim3(3 * DIM / 128, SEQ / 64), 256, 0, stream>>>(
            xnb, wqkv_b, nullptr, BIG, nullptr, qkvb, nullptr, 3 * DIM);
        rope_split_kernel<<<dim3(SEQ / 64, NH), 256, 0, stream>>>(qkvb, Qhb, Khb, Vtb);
        attn_mfma_kernel<<<dim3(NH, SEQ / 64), 256, 0, stream>>>(Qhb, Khb, Vtb, yb);
        // WO: 64x128, split-K=2, atomic residual+ls (512 blocks)
        mfma_gemm<1, 64, 128, 2, DIM><<<dim3(DIM / 128, SEQ / 64, 2), 256, 0, stream>>>(
            yb, wo_b, nullptr, BIG, h, nullptr, attn_ls + l * DIM, DIM);

        // ---- FFN block ----
        rmsnorm_kernel<true><<<SEQ, 256, 0, stream>>>(h, ffn_norm_w + l * DIM, xnb);
        // FUSED W1/W3 + silu: 64x128/BK32 dual-B, 1x4 waves, 704 blocks
        mfma_gemm_fused13<DIM><<<dim3(IDIM / 128, SEQ / 64), 256, 0, stream>>>(
            xnb, w1_b, w3_b, ffb, IDIM);
        // W2: 64x128, split-K=2, atomic residual+ls (512 blocks)
        mfma_gemm<1, 64, 128, 2, IDIM><<<dim3(DIM / 128, SEQ / 64, 2), 256, 0, stream>>>(
            ffb, w2_b, nullptr, BIG, h, nullptr, ffn_ls + l * DIM, DIM);
    }

    rmsnorm_kernel<false><<<SEQ, 256, 0, stream>>>(h, final_norm_w, out);
}

// Round 22
// 333.460 us; speedup vs baseline: 1.0338x; 1.0092x over previous
//
#include <hip/hip_runtime.h>
#include <math.h>

// Problem constants
#define SEQ 2048
#define DIM 1024
#define NH 16
#define HDIM 64
#define IDIM 2816
#define NL 2

typedef __attribute__((ext_vector_type(8))) short bf16x8;
typedef __attribute__((ext_vector_type(4))) float f32x4;

__device__ __forceinline__ unsigned short f2bf(float f) {
    unsigned int u = __float_as_uint(f);
    u = (u + 0x7fffu + ((u >> 16) & 1u)) >> 16;   // round-to-nearest-even
    return (unsigned short)u;
}
__device__ __forceinline__ float bf2f(unsigned short u) {
    return __uint_as_float((unsigned int)u << 16);
}

__device__ __forceinline__ void gl_lds16(const void* g, void* l) {
    __builtin_amdgcn_global_load_lds(
        (const __attribute__((address_space(1))) unsigned int*)g,
        (__attribute__((address_space(3))) unsigned int*)l, 16, 0, 0);
}

#define WAITVM(n) asm volatile("s_waitcnt vmcnt(" #n ")" ::: "memory")
#define BARRIER_PIN()                       \
    do {                                    \
        __builtin_amdgcn_s_barrier();       \
        __builtin_amdgcn_sched_barrier(0);  \
    } while (0)

// ---------------------------------------------------------------------------
// RMSNorm: one block per row, 256 threads, float4 loads.
// ---------------------------------------------------------------------------
template <bool BF16OUT>
__global__ __launch_bounds__(256) void rmsnorm_kernel(const float* __restrict__ in,
                                                      const float* __restrict__ w,
                                                      void* __restrict__ out) {
    const int row = blockIdx.x;
    const int t = threadIdx.x;
    const float4 v = ((const float4*)(in + (size_t)row * DIM))[t];
    float ss = v.x * v.x + v.y * v.y + v.z * v.z + v.w * v.w;
#pragma unroll
    for (int m = 1; m < 64; m <<= 1) ss += __shfl_xor(ss, m);
    __shared__ float red[4];
    if ((t & 63) == 0) red[t >> 6] = ss;
    __syncthreads();
    const float tot = red[0] + red[1] + red[2] + red[3];
    const float r = 1.0f / sqrtf(tot * (1.0f / DIM) + 1e-5f);
    const float4 wv = ((const float4*)w)[t];
    float o0 = v.x * r * wv.x, o1 = v.y * r * wv.y;
    float o2 = v.z * r * wv.z, o3 = v.w * r * wv.w;
    if (BF16OUT) {
        ushort4 o = {f2bf(o0), f2bf(o1), f2bf(o2), f2bf(o3)};
        ((ushort4*)((unsigned short*)out + (size_t)row * DIM))[t] = o;
    } else {
        float4 o = {o0, o1, o2, o3};
        ((float4*)((float*)out + (size_t)row * DIM))[t] = o;
    }
}

// ---------------------------------------------------------------------------
// Weight conversion fp32 -> bf16 for ONE layer into contiguous wbuf.
// ---------------------------------------------------------------------------
#define WQKV_OFF 0
#define WO_OFF   3145728
#define W1_OFF   4194304
#define W3_OFF   7077888
#define W2_OFF   9961472
#define WTOT     12845056

__global__ __launch_bounds__(256) void convert_weights_kernel(
    const float* __restrict__ wqkv, const float* __restrict__ wo,
    const float* __restrict__ w1, const float* __restrict__ w3,
    const float* __restrict__ w2, unsigned short* __restrict__ out) {
    const size_t i8 = ((size_t)blockIdx.x * 256 + threadIdx.x) * 8;
    const float* src;
    size_t local;
    if (i8 < WO_OFF)      { src = wqkv; local = i8 - WQKV_OFF; }
    else if (i8 < W1_OFF) { src = wo;   local = i8 - WO_OFF; }
    else if (i8 < W3_OFF) { src = w1;   local = i8 - W1_OFF; }
    else if (i8 < W2_OFF) { src = w3;   local = i8 - W3_OFF; }
    else                  { src = w2;   local = i8 - W2_OFF; }
    const float4 v0 = *(const float4*)(src + local);
    const float4 v1 = *(const float4*)(src + local + 4);
    ushort4 o0 = {f2bf(v0.x), f2bf(v0.y), f2bf(v0.z), f2bf(v0.w)};
    ushort4 o1 = {f2bf(v1.x), f2bf(v1.y), f2bf(v1.z), f2bf(v1.w)};
    *(ushort4*)(out + i8) = o0;
    *(ushort4*)(out + i8 + 4) = o1;
}

// ---------------------------------------------------------------------------
// bf16 MFMA GEMM. Tile BM x BN, BK=64, 2-deep double-buffer, counted vmcnt,
// T2 chunk-XOR swizzle, XCD swizzle with COLUMN-major block mapping.
// COMPILE-TIME K (KC); hoisted fragment offsets; unroll-2 K-loop.
// EPI 1: KSPLIT==1: Cf += acc*ls[col]; KSPLIT>1: atomicAdd(Cf, acc*ls[col])
// EPI 3: Cb = bf16(acc)
// ---------------------------------------------------------------------------
template <int EPI, int BM, int BN, int KSPLIT, int KC>
__global__ __launch_bounds__(256) void mfma_gemm(
    const unsigned short* __restrict__ A,
    const unsigned short* __restrict__ B,
    const unsigned short* __restrict__ Bhi, int nsplit,
    float* __restrict__ Cf,
    unsigned short* __restrict__ Cb,
    const float* __restrict__ ls,
    int N) {
    constexpr int K = KC;
    constexpr int MI = BM / 32;
    constexpr int NJ = BN / 32;
    constexpr int L = (BM + BN) / 32;
    constexpr int NT = K / KSPLIT / 64;
    static_assert(L == 6 || L == 8, "WAITVM literals cover L=6,8");
    __shared__ unsigned short As[2][BM * 64];
    __shared__ unsigned short Bs[2][BN * 64];

    const int tid = threadIdx.x;

    const int nwg = gridDim.x * gridDim.y;
    const int orig = blockIdx.y * gridDim.x + blockIdx.x;
    const int swz = (orig & 7) * (nwg >> 3) + (orig >> 3);
    const int bx = swz / gridDim.y;        // column-major: by fast
    const int by = swz % gridDim.y;
    const int m0 = by * BM;
    const int ncol0 = bx * BN;

    const unsigned short* Bp = B;
    int n0 = ncol0;
    if (n0 >= nsplit) { Bp = Bhi; n0 -= nsplit; }

    const int Koff = (KSPLIT > 1) ? blockIdx.z * (K / KSPLIT) : 0;

    const int r0 = tid >> 3;               // 0..31
    const int cswz = (tid & 7) ^ (r0 & 7); // swizzled source chunk
    const unsigned short* Ag = A + (size_t)(m0 + r0) * K + Koff + cswz * 8;
    const unsigned short* Bg = Bp + (size_t)(n0 + r0) * K + Koff + cswz * 8;

    const int lane = tid & 63;
    const int wid = tid >> 6;
    const int wr = (wid >> 1) * (BM / 2);
    const int wc = (wid & 1) * (BN / 2);
    const int fr = lane & 15;
    const int hi = lane >> 4;

    // hoisted fragment LDS offsets (elements), t/buf-invariant
    int offA[MI][2], offB[NJ][2];
#pragma unroll
    for (int m = 0; m < MI; ++m)
#pragma unroll
        for (int kw = 0; kw < 2; ++kw) {
            const int R = wr + m * 16 + fr, c = kw * 4 + hi;
            offA[m][kw] = R * 64 + ((c ^ (R & 7)) << 3);
        }
#pragma unroll
    for (int n = 0; n < NJ; ++n)
#pragma unroll
        for (int kw = 0; kw < 2; ++kw) {
            const int R = wc + n * 16 + fr, c = kw * 4 + hi;
            offB[n][kw] = R * 64 + ((c ^ (R & 7)) << 3);
        }

    f32x4 acc[MI][NJ] = {};

    auto stage = [&](int buf, int kk) {
#pragma unroll
        for (int q = 0; q < BM / 32; ++q)
            gl_lds16(Ag + (size_t)(q * 32) * K + kk, &As[buf][q * 2048 + tid * 8]);
#pragma unroll
        for (int q = 0; q < BN / 32; ++q)
            gl_lds16(Bg + (size_t)(q * 32) * K + kk, &Bs[buf][q * 2048 + tid * 8]);
    };

    auto compute_tile = [&](int buf) {
        bf16x8 a[MI][2], b[NJ][2];
#pragma unroll
        for (int m = 0; m < MI; ++m)
#pragma unroll
            for (int kw = 0; kw < 2; ++kw)
                a[m][kw] = *(const bf16x8*)&As[buf][offA[m][kw]];
#pragma unroll
        for (int n = 0; n < NJ; ++n)
#pragma unroll
            for (int kw = 0; kw < 2; ++kw)
                b[n][kw] = *(const bf16x8*)&Bs[buf][offB[n][kw]];
        __builtin_amdgcn_s_setprio(1);
#pragma unroll
        for (int kw = 0; kw < 2; ++kw)
#pragma unroll
            for (int m = 0; m < MI; ++m)
#pragma unroll
                for (int n = 0; n < NJ; ++n)
                    acc[m][n] = __builtin_amdgcn_mfma_f32_16x16x32_bf16(
                        a[m][kw], b[n][kw], acc[m][n], 0, 0, 0);
        __builtin_amdgcn_s_setprio(0);
    };

    stage(0, 0);
    stage(1, 64);

    int buf = 0;
#pragma unroll 2
    for (int t = 0; t < NT - 1; ++t) {
        if constexpr (L == 6) WAITVM(6); else WAITVM(8);
        BARRIER_PIN();
        compute_tile(buf);
        asm volatile("s_waitcnt lgkmcnt(0)" ::: "memory");
        BARRIER_PIN();
        if (t + 2 < NT) stage(buf, (t + 2) * 64);
        buf ^= 1;
    }
    WAITVM(0);
    BARRIER_PIN();
    compute_tile(buf);

    const int erow = m0 + wr + hi * 4;
    const int ecol = ncol0 + wc + fr;
#pragma unroll
    for (int m = 0; m < MI; ++m) {
#pragma unroll
        for (int n = 0; n < NJ; ++n) {
            const f32x4 v = acc[m][n];
            const int row = erow + m * 16;
            const int col = ecol + n * 16;
            if (EPI == 1) {
                const float lv = ls[col];
#pragma unroll
                for (int j = 0; j < 4; ++j) {
                    float* p = Cf + (size_t)(row + j) * N + col;
                    if (KSPLIT > 1) atomicAdd(p, v[j] * lv);
                    else            *p = *p + v[j] * lv;
                }
            } else {
#pragma unroll
                for (int j = 0; j < 4; ++j)
                    Cb[(size_t)(row + j) * N + col] = f2bf(v[j]);
            }
        }
    }
}

// ---------------------------------------------------------------------------
// FUSED W1/W3 GEMM + silu-mul epilogue. Tile 64x128, BK=32, dual-B,
// 1x4 wave split, 704 blocks, LDS 40 KB. COMPILE-TIME K; hoisted offsets.
// out[s][n] = silu(A@w1^T) * (A@w3^T).
// LDS virtual-row layout: elem(R, c in 0..3): vr=R>>1,
//   slot=((R&1)*4+c)^(vr&7), offset = vr*64 + slot*8.
// Stage: issue q covers vr q*32+(tid>>3); uc=(tid&7)^((tid>>3)&7);
// global row = q*64 + 2*(tid>>3)+(uc>>2), k-chunk = uc&3;
// LDS dest = q*2048 + tid*8. A: 1 issue; B1,B3: 2 each -> L=5, WAITVM(5).
// ---------------------------------------------------------------------------
template <int KC>
__global__ __launch_bounds__(256) void mfma_gemm_fused13(
    const unsigned short* __restrict__ A,
    const unsigned short* __restrict__ B1,
    const unsigned short* __restrict__ B3,
    unsigned short* __restrict__ Out,
    int N) {
    constexpr int K = KC;
    constexpr int NT = K / 32;
    __shared__ unsigned short As[2][64 * 32];
    __shared__ unsigned short Bs[2][128 * 32];
    __shared__ unsigned short B2s[2][128 * 32];

    const int tid = threadIdx.x;

    const int nwg = gridDim.x * gridDim.y;
    const int orig = blockIdx.y * gridDim.x + blockIdx.x;
    const int swz = (orig & 7) * (nwg >> 3) + (orig >> 3);
    const int bx = swz / gridDim.y;        // column-major: by fast
    const int by = swz % gridDim.y;
    const int m0 = by * 64;
    const int n0 = bx * 128;

    const int uc = (tid & 7) ^ ((tid >> 3) & 7);
    const int srow = 2 * (tid >> 3) + (uc >> 2);
    const int skof = (uc & 3) * 8;
    const unsigned short* Ag = A + (size_t)(m0 + srow) * K + skof;
    const unsigned short* B1g = B1 + (size_t)(n0 + srow) * K + skof;
    const unsigned short* B3g = B3 + (size_t)(n0 + srow) * K + skof;

    const int lane = tid & 63;
    const int wid = tid >> 6;
    const int wc = wid * 32;               // 1x4 wave split
    const int fr = lane & 15;
    const int hi = lane >> 4;

    // hoisted fragment LDS offsets (elements)
    int offA[4], offB[2];
#pragma unroll
    for (int m = 0; m < 4; ++m) {
        const int R = m * 16 + fr;
        const int vr = R >> 1;
        offA[m] = vr * 64 + ((((R & 1) * 4 + hi) ^ (vr & 7)) << 3);
    }
#pragma unroll
    for (int n = 0; n < 2; ++n) {
        const int R = wc + n * 16 + fr;
        const int vr = R >> 1;
        offB[n] = vr * 64 + ((((R & 1) * 4 + hi) ^ (vr & 7)) << 3);
    }

    f32x4 acc[4][2] = {};
    f32x4 acc2[4][2] = {};

    auto stage = [&](int buf, int kk) {
        gl_lds16(Ag + kk, &As[buf][tid * 8]);
#pragma unroll
        for (int q = 0; q < 2; ++q)
            gl_lds16(B1g + (size_t)(q * 64) * K + kk, &Bs[buf][q * 2048 + tid * 8]);
#pragma unroll
        for (int q = 0; q < 2; ++q)
            gl_lds16(B3g + (size_t)(q * 64) * K + kk, &B2s[buf][q * 2048 + tid * 8]);
    };

    auto compute_tile = [&](int buf) {
        bf16x8 a[4], b[2], b2[2];
#pragma unroll
        for (int m = 0; m < 4; ++m)
            a[m] = *(const bf16x8*)&As[buf][offA[m]];
#pragma unroll
        for (int n = 0; n < 2; ++n)
            b[n] = *(const bf16x8*)&Bs[buf][offB[n]];
#pragma unroll
        for (int n = 0; n < 2; ++n)
            b2[n] = *(const bf16x8*)&B2s[buf][offB[n]];
        __builtin_amdgcn_s_setprio(1);
#pragma unroll
        for (int m = 0; m < 4; ++m)
#pragma unroll
            for (int n = 0; n < 2; ++n)
                acc[m][n] = __builtin_amdgcn_mfma_f32_16x16x32_bf16(
                    a[m], b[n], acc[m][n], 0, 0, 0);
#pragma unroll
        for (int m = 0; m < 4; ++m)
#pragma unroll
            for (int n = 0; n < 2; ++n)
                acc2[m][n] = __builtin_amdgcn_mfma_f32_16x16x32_bf16(
                    a[m], b2[n], acc2[m][n], 0, 0, 0);
        __builtin_amdgcn_s_setprio(0);
    };

    stage(0, 0);
    stage(1, 32);

    int buf = 0;
#pragma unroll 2
    for (int t = 0; t < NT - 1; ++t) {
        WAITVM(5);                          // tile t resident (t+1's 5 remain)
        BARRIER_PIN();
        compute_tile(buf);
        asm volatile("s_waitcnt lgkmcnt(0)" ::: "memory");
        BARRIER_PIN();
        if (t + 2 < NT) stage(buf, (t + 2) * 32);
        buf ^= 1;
    }
    WAITVM(0);
    BARRIER_PIN();
    compute_tile(buf);

    const int erow = m0 + hi * 4;
    const int ecol = n0 + wc + fr;
#pragma unroll
    for (int m = 0; m < 4; ++m) {
#pragma unroll
        for (int n = 0; n < 2; ++n) {
            const f32x4 g = acc[m][n];
            const f32x4 u = acc2[m][n];
            const int row = erow + m * 16;
            const int col = ecol + n * 16;
#pragma unroll
            for (int j = 0; j < 4; ++j) {
                const float x = g[j];
                Out[(size_t)(row + j) * N + col] =
                    f2bf(x / (1.0f + __expf(-x)) * u[j]);
            }
        }
    }
}

// ---------------------------------------------------------------------------
// RoPE + head-split + V-transpose. Reads bf16 qkv [S][3*DIM]; writes
// Qh,Kh [H][S][HD] (rope'd, bf16) and Vt [H][HD][S] (bf16, LDS-transposed).
// ---------------------------------------------------------------------------
__global__ __launch_bounds__(256) void rope_split_kernel(
    const unsigned short* __restrict__ qkv,
    unsigned short* __restrict__ Qh,
    unsigned short* __restrict__ Kh,
    unsigned short* __restrict__ Vt) {
    const int st = blockIdx.x;
    const int h = blockIdx.y;
    const int tid = threadIdx.x;
    const int srow = tid >> 2;
    const int scol = (tid & 3) * 16;
    const int s = st * 64 + srow;
    __shared__ unsigned short Vl[64][72];

    const unsigned short* base = qkv + (size_t)s * (3 * DIM) + h * HDIM + scol;

    unsigned short qv[16], kv[16], vv[16];
    *(bf16x8*)&qv[0] = *(const bf16x8*)(base);
    *(bf16x8*)&qv[8] = *(const bf16x8*)(base + 8);
    *(bf16x8*)&kv[0] = *(const bf16x8*)(base + DIM);
    *(bf16x8*)&kv[8] = *(const bf16x8*)(base + DIM + 8);
    *(bf16x8*)&vv[0] = *(const bf16x8*)(base + 2 * DIM);
    *(bf16x8*)&vv[8] = *(const bf16x8*)(base + 2 * DIM + 8);

    // -2*ln(10000)/64
    const float FC = -0.28782313662425572f;
    unsigned short qo[16], ko[16];
#pragma unroll
    for (int i = 0; i < 8; ++i) {
        const int p = scol / 2 + i;
        const float freq = __expf(FC * (float)p);
        const float ang = (float)s * freq;
        float sn, cs;
        sincosf(ang, &sn, &cs);
        const float q0 = bf2f(qv[2 * i]), q1 = bf2f(qv[2 * i + 1]);
        const float k0 = bf2f(kv[2 * i]), k1 = bf2f(kv[2 * i + 1]);
        qo[2 * i]     = f2bf(q0 * cs - q1 * sn);
        qo[2 * i + 1] = f2bf(q1 * cs + q0 * sn);
        ko[2 * i]     = f2bf(k0 * cs - k1 * sn);
        ko[2 * i + 1] = f2bf(k1 * cs + k0 * sn);
    }
    unsigned short* qdst = Qh + ((size_t)h * SEQ + s) * HDIM + scol;
    unsigned short* kdst = Kh + ((size_t)h * SEQ + s) * HDIM + scol;
    *(bf16x8*)qdst = *(const bf16x8*)&qo[0];
    *(bf16x8*)(qdst + 8) = *(const bf16x8*)&qo[8];
    *(bf16x8*)kdst = *(const bf16x8*)&ko[0];
    *(bf16x8*)(kdst + 8) = *(const bf16x8*)&ko[8];

#pragma unroll
    for (int i = 0; i < 16; ++i) Vl[scol + i][srow] = vv[i];
    __syncthreads();
    const int d = tid >> 2;
    const int c0 = (tid & 3) * 16;
    unsigned short* vdst = Vt + ((size_t)h * HDIM + d) * SEQ + st * 64 + c0;
    *(bf16x8*)vdst = *(const bf16x8*)&Vl[d][c0];
    *(bf16x8*)(vdst + 8) = *(const bf16x8*)&Vl[d][c0 + 8];
}

// ---------------------------------------------------------------------------
// MFMA flash attention v2c (bf16 in, fp32 acc, causal). Fixed-max softmax,
// KVBLK=64, double-buffered K/V LDS with reg prefetch, Q direct to regs.
// CHANGE vs v2b: single barrier per KV tile. The leading barrier was
// redundant: readers of buf[cur] at iter kb-2 retire (lgkm-waited by their
// MFMA consumers) before that wave reaches barrier B(kb-1); any wave only
// rewrites buf[cur] at iter kb after passing B(kb-1). Pl is wave-private.
// ---------------------------------------------------------------------------
__global__ __launch_bounds__(256) void attn_mfma_kernel(
    const unsigned short* __restrict__ Qh,
    const unsigned short* __restrict__ Kh,
    const unsigned short* __restrict__ Vt,
    unsigned short* __restrict__ y) {
    const int h = blockIdx.x;
    const int qt = blockIdx.y;
    const int qb = (qt < 16) ? qt : 47 - qt;   // pair-balance remap

    __shared__ unsigned short Kl[2][64][72];
    __shared__ unsigned short Vl[2][64][72];
    __shared__ unsigned short Pl[64][72];

    const int tid = threadIdx.x;
    const int lane = tid & 63;
    const int w = tid >> 6;
    const int fr = lane & 15;
    const int fk = (lane >> 4) * 8;
    const int rg = (lane >> 4) * 4;
    const int srow = tid >> 2;
    const int sc8 = (tid & 3) * 8;

    bf16x8 qa[2];
    {
        const unsigned short* qsrc =
            Qh + ((size_t)h * SEQ + qb * 64 + w * 16 + fr) * HDIM;
        qa[0] = *(const bf16x8*)(qsrc + fk);
        qa[1] = *(const bf16x8*)(qsrc + 32 + fk);
    }

    bf16x8 kr0, kr1, vr0, vr1;
    {
        const unsigned short* ks = Kh + ((size_t)h * SEQ + srow) * HDIM + sc8;
        kr0 = *(const bf16x8*)ks;
        kr1 = *(const bf16x8*)(ks + 32);
        const unsigned short* vs = Vt + ((size_t)h * HDIM + srow) * SEQ + sc8;
        vr0 = *(const bf16x8*)vs;
        vr1 = *(const bf16x8*)(vs + 32);
    }

    float l_[4] = {0.0f, 0.0f, 0.0f, 0.0f};
    f32x4 O[4] = {};

    for (int kb = 0; kb <= qb; ++kb) {
        const int cur = kb & 1;
        *(bf16x8*)&Kl[cur][srow][sc8] = kr0;
        *(bf16x8*)&Kl[cur][srow][sc8 + 32] = kr1;
        *(bf16x8*)&Vl[cur][srow][sc8] = vr0;
        *(bf16x8*)&Vl[cur][srow][sc8 + 32] = vr1;
        __syncthreads();   // single barrier/tile: writes visible, prior reads done

        if (kb < qb) {
            const unsigned short* ks = Kh + ((size_t)h * SEQ + (kb + 1) * 64 + srow) * HDIM + sc8;
            kr0 = *(const bf16x8*)ks;
            kr1 = *(const bf16x8*)(ks + 32);
            const unsigned short* vs = Vt + ((size_t)h * HDIM + srow) * SEQ + (kb + 1) * 64 + sc8;
            vr0 = *(const bf16x8*)vs;
            vr1 = *(const bf16x8*)(vs + 32);
        }

        f32x4 sa[4] = {};
        __builtin_amdgcn_s_setprio(1);
#pragma unroll
        for (int ks2 = 0; ks2 < 2; ++ks2)
#pragma unroll
            for (int n = 0; n < 4; ++n) {
                const bf16x8 kf = *(const bf16x8*)&Kl[cur][n * 16 + fr][ks2 * 32 + fk];
                sa[n] = __builtin_amdgcn_mfma_f32_16x16x32_bf16(qa[ks2], kf, sa[n], 0, 0, 0);
            }
        __builtin_amdgcn_s_setprio(0);

        const bool diag = (kb == qb);
#pragma unroll
        for (int n = 0; n < 4; ++n) {
            const int col = n * 16 + fr;
#pragma unroll
            for (int j = 0; j < 4; ++j) {
                const float sv = sa[n][j] * 0.125f;
                float e = __expf(fminf(sv, 30.0f));
                if (diag && col > rg + j) e = 0.0f;
                l_[j] += e;
                Pl[w * 16 + rg + j][col] = f2bf(e);
            }
        }

        __builtin_amdgcn_s_setprio(1);
#pragma unroll
        for (int ks2 = 0; ks2 < 2; ++ks2) {
            const bf16x8 pa = *(const bf16x8*)&Pl[w * 16 + fr][ks2 * 32 + fk];
#pragma unroll
            for (int nd = 0; nd < 4; ++nd) {
                const bf16x8 vf = *(const bf16x8*)&Vl[cur][nd * 16 + fr][ks2 * 32 + fk];
                O[nd] = __builtin_amdgcn_mfma_f32_16x16x32_bf16(pa, vf, O[nd], 0, 0, 0);
            }
        }
        __builtin_amdgcn_s_setprio(0);
    }

#pragma unroll
    for (int j = 0; j < 4; ++j) {
#pragma unroll
        for (int msk = 1; msk < 16; msk <<= 1) l_[j] += __shfl_xor(l_[j], msk);
    }

#pragma unroll
    for (int j = 0; j < 4; ++j) {
        const float inv = 1.0f / l_[j];
        unsigned short* dst = y + (size_t)(qb * 64 + w * 16 + rg + j) * DIM + h * HDIM + fr;
#pragma unroll
        for (int nd = 0; nd < 4; ++nd)
            dst[nd * 16] = f2bf(O[nd][j] * inv);
    }
}

// ---------------------------------------------------------------------------
// Host launcher
// ---------------------------------------------------------------------------
extern "C" void kernel_launch(void* const* d_in, const int* in_sizes, int n_in,
                              void* d_out, int out_size, void* d_ws, size_t ws_size,
                              hipStream_t stream) {
    const float* x            = (const float*)d_in[0];
    const float* wqkv         = (const float*)d_in[1];
    const float* wo           = (const float*)d_in[2];
    const float* w1           = (const float*)d_in[3];
    const float* w2           = (const float*)d_in[4];
    const float* w3           = (const float*)d_in[5];
    const float* attn_norm_w  = (const float*)d_in[6];
    const float* ffn_norm_w   = (const float*)d_in[7];
    const float* attn_ls      = (const float*)d_in[8];
    const float* ffn_ls       = (const float*)d_in[9];
    const float* final_norm_w = (const float*)d_in[10];
    float* out = (float*)d_out;

    // Workspace layout (bytes):
    //   h    f32  [0,        8388608)
    //   xnb  bf16 [8388608, 12582912)
    //   yb   bf16 [12582912,16777216)
    //   scratch   [16777216,41943040): qkvb | Qh | Kh | Vt
    //   ffb  bf16 [41943040,46137344)
    //   wbuf bf16 [46137344,71827456)
    char* ws = (char*)d_ws;
    float*          h     = (float*)ws;
    unsigned short* xnb   = (unsigned short*)(ws + 8388608);
    unsigned short* yb    = (unsigned short*)(ws + 12582912);
    unsigned short* qkvb  = (unsigned short*)(ws + 16777216);
    unsigned short* Qhb   = (unsigned short*)(ws + 29360128);
    unsigned short* Khb   = (unsigned short*)(ws + 33554432);
    unsigned short* Vtb   = (unsigned short*)(ws + 37748736);
    unsigned short* ffb   = (unsigned short*)(ws + 41943040);
    unsigned short* wbuf  = (unsigned short*)(ws + 46137344);

    unsigned short* wqkv_b = wbuf + WQKV_OFF;
    unsigned short* wo_b   = wbuf + WO_OFF;
    unsigned short* w1_b   = wbuf + W1_OFF;
    unsigned short* w3_b   = wbuf + W3_OFF;
    unsigned short* w2_b   = wbuf + W2_OFF;

    const int BIG = 1 << 30;

    hipMemcpyAsync(h, x, (size_t)SEQ * DIM * sizeof(float),
                   hipMemcpyDeviceToDevice, stream);

    for (int l = 0; l < NL; ++l) {
        convert_weights_kernel<<<WTOT / 2048, 256, 0, stream>>>(
            wqkv + (size_t)l * 3 * DIM * DIM, wo + (size_t)l * DIM * DIM,
            w1 + (size_t)l * IDIM * DIM, w3 + (size_t)l * IDIM * DIM,
            w2 + (size_t)l * DIM * IDIM, wbuf);

        // ---- attention block ----
        rmsnorm_kernel<true><<<SEQ, 256, 0, stream>>>(h, attn_norm_w + l * DIM, xnb);
        // QKV: 64x128, 768 blocks (3/CU)
        mfma_gemm<3, 64, 128, 1, DIM><<<dim3(3 * DIM / 128, SEQ / 64), 256, 0, stream>>>(
            xnb, wqkv_b, nullptr, BIG, nullptr, qkvb, nullptr, 3 * DIM);
        rope_split_kernel<<<dim3(SEQ / 64, NH), 256, 0, stream>>>(qkvb, Qhb, Khb, Vtb);
        attn_mfma_kernel<<<dim3(NH, SEQ / 64), 256, 0, stream>>>(Qhb, Khb, Vtb, yb);
        // WO: 64x128, split-K=2, atomic residual+ls (512 blocks)
        mfma_gemm<1, 64, 128, 2, DIM><<<dim3(DIM / 128, SEQ / 64, 2), 256, 0, stream>>>(
            yb, wo_b, nullptr, BIG, h, nullptr, attn_ls + l * DIM, DIM);

        // ---- FFN block ----
        rmsnorm_kernel<true><<<SEQ, 256, 0, stream>>>(h, ffn_norm_w + l * DIM, xnb);
        // FUSED W1/W3 + silu: 64x128/BK32 dual-B, 1x4 waves, 704 blocks
        mfma_gemm_fused13<DIM><<<dim3(IDIM / 128, SEQ / 64), 256, 0, stream>>>(
            xnb, w1_b, w3_b, ffb, IDIM);
        // W2: 64x128, split-K=2, atomic residual+ls (512 blocks)
        mfma_gemm<1, 64, 128, 2, IDIM><<<dim3(DIM / 128, SEQ / 64, 2), 256, 0, stream>>>(
            ffb, w2_b, nullptr, BIG, h, nullptr, ffn_ls + l * DIM, DIM);
    }

    rmsnorm_kernel<false><<<SEQ, 256, 0, stream>>>(h, final_norm_w, out);
}